// Round 8
// baseline (117.548 us; speedup 1.0000x reference)
//
#include <hip/hip_runtime.h>
#include <hip/hip_bf16.h>

// InfoNCE (n_views=1): loss = mean_i [ LSE_{j!=i}(f_i . f_j / T) - f_i . f_{c_i} / T ].
// FP8 (OCP e4m3) upper-triangle MFMA F F^T + fixed-max softmax partials.
// Feats PRE-PERMUTED per 128-B K-window so the LDS reader is one conflict-free
// ds_read_b128 per fragment pair (R7: conflicts 4.26e6 -> 0, sim 46 -> <43.5).
// R8: double-buffered LDS staging — prefetch tile kt+1 during compute of kt so
// the vmcnt(0) drain at the barrier is covered by ~5000 cyc of MFMA. One
// barrier per K-iteration (was 2), last barrier dropped. LDS 32 -> 64 KB
// (cap 2 blocks/CU = current achieved occupancy, no regression).

typedef float f32x4 __attribute__((ext_vector_type(4)));
typedef long l2 __attribute__((ext_vector_type(2)));

#define AS1 __attribute__((address_space(1)))
#define AS3 __attribute__((address_space(3)))

constexpr int NB = 8192;   // batch
constexpr int ND = 512;    // dim
constexpr int NBLK = NB / 4;   // combine blocks (4 rows each)
constexpr float INV_T = 1.0f / 0.07f;

__device__ inline unsigned short f2bf(float f) {
    union { float f; unsigned int u; } v; v.f = f;
    unsigned int u = v.u;
    u = u + 0x7fffu + ((u >> 16) & 1u);   // round-to-nearest-even
    return (unsigned short)(u >> 16);
}
__device__ inline float bf2f(unsigned short s) {
    union { unsigned int u; float f; } v; v.u = ((unsigned int)s) << 16;
    return v.f;
}

// ------- Kernel 1: normalize rows; write PERMUTED fp8 feats + row-major bf16 -------
__global__ __launch_bounds__(256) void norm_kernel(const float* __restrict__ x,
                                                   unsigned char* __restrict__ feats8,
                                                   unsigned short* __restrict__ featsbf) {
    const int wave = threadIdx.x >> 6;
    const int lane = threadIdx.x & 63;
    const int row  = blockIdx.x * 4 + wave;
    const float4* xr = (const float4*)(x + (size_t)row * ND);
    float4 a = xr[2 * lane];       // cols 8*lane   .. +3
    float4 b = xr[2 * lane + 1];   // cols 8*lane+4 .. +7
    float ss = a.x*a.x + a.y*a.y + a.z*a.z + a.w*a.w
             + b.x*b.x + b.y*b.y + b.z*b.z + b.w*b.w;
    #pragma unroll
    for (int m = 32; m >= 1; m >>= 1) ss += __shfl_xor(ss, m);
    float scale = 1.0f / fmaxf(sqrtf(ss), 1e-12f);
    a.x *= scale; a.y *= scale; a.z *= scale; a.w *= scale;
    b.x *= scale; b.y *= scale; b.z *= scale; b.w *= scale;

    // bf16 copy, row-major (contiguous 8 shorts per lane) — used by combine's dot
    uint4 ub;
    ub.x = (unsigned)f2bf(a.x) | ((unsigned)f2bf(a.y) << 16);
    ub.y = (unsigned)f2bf(a.z) | ((unsigned)f2bf(a.w) << 16);
    ub.z = (unsigned)f2bf(b.x) | ((unsigned)f2bf(b.y) << 16);
    ub.w = (unsigned)f2bf(b.z) | ((unsigned)f2bf(b.w) << 16);
    ((uint4*)(featsbf + (size_t)row * ND))[lane] = ub;

    // fp8 e4m3, PERMUTED: lane holds original 8-B piece L (k = 8L..8L+7), i.e.
    // kt = L>>4, ks = (L>>2)&3, q = L&3.  New 8-B slot within the row:
    //   slot = kt*16 + (ks2*4 + q)*2 + (ks&1),  ks2 = ks>>1
    int w0 = __builtin_amdgcn_cvt_pk_fp8_f32(a.x, a.y, 0, false);
    w0     = __builtin_amdgcn_cvt_pk_fp8_f32(a.z, a.w, w0, true);
    int w1 = __builtin_amdgcn_cvt_pk_fp8_f32(b.x, b.y, 0, false);
    w1     = __builtin_amdgcn_cvt_pk_fp8_f32(b.z, b.w, w1, true);
    uint2 u8; u8.x = (unsigned)w0; u8.y = (unsigned)w1;
    const int L    = lane;
    const int slot = ((L >> 4) << 4) + ((((L >> 3) & 1) * 4 + (L & 3)) << 1) + ((L >> 2) & 1);
    ((uint2*)(feats8 + (size_t)row * ND))[slot] = u8;
}

// ------- Kernel 2: upper-tri 128x128 tiles, fp8 MFMA, double-buffered staging ------
// 2080 blocks -> (bi <= bj). 4 waves = 2x2 quadrants of 64x64. BK=128 fp8 bytes.
// LDS(r, u) = G(r, kt, u ^ (r&7)); reader fetches unit (ks2*4+q)^(r&7) as b128.
__global__ __launch_bounds__(256) void sim_lse_kernel(const unsigned char* __restrict__ feats8,
                                                      float* __restrict__ partials) {
    __shared__ unsigned char sA[2][128 * 128];
    __shared__ unsigned char sB[2][128 * 128];

    const int tid  = threadIdx.x;
    const int lane = tid & 63;
    const int wave = tid >> 6;
    const int wr   = wave >> 1;     // wave row quadrant (0..1)
    const int wc   = wave & 1;      // wave col quadrant (0..1)

    // decode upper-triangle pair: t -> (bi <= bj)
    int t = blockIdx.x;
    int bj = (int)((sqrtf(8.0f * (float)t + 1.0f) - 1.0f) * 0.5f);
    while ((bj + 1) * (bj + 2) / 2 <= t) ++bj;
    while (bj * (bj + 1) / 2 > t) --bj;
    const int bi = t - bj * (bj + 1) / 2;

    const int rowA0 = bi * 128;
    const int rowB0 = bj * 128;

    f32x4 acc[4][4] = {};

    const int m    = lane & 15;
    const int quad = lane >> 4;
    const int sw   = m & 7;         // unit swizzle (row & 7 == m & 7)

    auto stage = [&](int buf, int kt) {
        const int k0 = kt * 128;      // byte offset within the 512 B fp8 row
        #pragma unroll
        for (int r = 0; r < 4; ++r) {
            int c   = r * 256 + tid;  // 16B chunk id (1024 per array)
            int row = c >> 3;
            int k8g = (c & 7) ^ (row & 7);
            const unsigned char* ga = feats8 + (size_t)(rowA0 + row) * ND + k0 + k8g * 16;
            const unsigned char* gb = feats8 + (size_t)(rowB0 + row) * ND + k0 + k8g * 16;
            __builtin_amdgcn_global_load_lds((const AS1 void*)ga, (AS3 void*)(&sA[buf][c * 16]), 16, 0, 0);
            __builtin_amdgcn_global_load_lds((const AS1 void*)gb, (AS3 void*)(&sB[buf][c * 16]), 16, 0, 0);
        }
    };
    auto compute = [&](int buf) {
        #pragma unroll
        for (int ks2 = 0; ks2 < 2; ++ks2) {
            const int uoff = ((ks2 * 4 + quad) ^ sw) << 4;   // swizzled 16B unit
            l2 afr[4], bfr[4];
            #pragma unroll
            for (int s = 0; s < 4; ++s) {
                afr[s] = *(const l2*)(&sA[buf][(wr * 64 + s * 16 + m) * 128 + uoff]);
                bfr[s] = *(const l2*)(&sB[buf][(wc * 64 + s * 16 + m) * 128 + uoff]);
            }
            #pragma unroll
            for (int e = 0; e < 2; ++e)
                #pragma unroll
                for (int si = 0; si < 4; ++si)
                    #pragma unroll
                    for (int sj = 0; sj < 4; ++sj)
                        acc[si][sj] = __builtin_amdgcn_mfma_f32_16x16x32_fp8_fp8(
                            afr[si][e], bfr[sj][e], acc[si][sj], 0, 0, 0);
        }
    };

    // Software pipeline: prefetch kt+1 into the idle buffer while computing kt.
    // Barrier at end of kt drains the prefetch (overlapped with compute) and
    // guarantees all waves finished reading buf[cur] before it is re-staged.
    stage(0, 0);
    __syncthreads();
    #pragma unroll
    for (int kt = 0; kt < 4; ++kt) {
        const int cur = kt & 1;
        if (kt < 3) stage(1 - cur, kt + 1);
        compute(cur);
        if (kt < 3) __syncthreads();
    }

    // ---- Transform in place: acc <- exp((sim-1)/T), diagonal -> 0 ----
    // C/D layout (16x16x32, dtype-independent): col = lane&15, row = quad*4 + reg.
    const float C1 = INV_T * 1.4426950408889634f;   // log2(e)/T
    #pragma unroll
    for (int si = 0; si < 4; ++si) {
        #pragma unroll
        for (int sj = 0; sj < 4; ++sj) {
            const int gcol = rowB0 + wc * 64 + sj * 16 + m;
            #pragma unroll
            for (int r = 0; r < 4; ++r) {
                const int grow = rowA0 + wr * 64 + si * 16 + quad * 4 + r;
                float e = exp2f(fmaf(acc[si][sj][r], C1, -C1));
                acc[si][sj][r] = (grow == gcol) ? 0.0f : e;
            }
        }
    }

    // ---- Row pass: per-row sumexp over this wave's 64 cols ----
    #pragma unroll
    for (int si = 0; si < 4; ++si) {
        #pragma unroll
        for (int r = 0; r < 4; ++r) {
            float s = acc[si][0][r] + acc[si][1][r] + acc[si][2][r] + acc[si][3][r];
            #pragma unroll
            for (int msk = 1; msk < 16; msk <<= 1) s += __shfl_xor(s, msk);
            if (m == 0) {
                const int grow = rowA0 + wr * 64 + si * 16 + quad * 4 + r;
                partials[(size_t)grow * 128 + bj * 2 + wc] = s;
            }
        }
    }

    // ---- Col pass (off-diagonal tiles only): sim[j][i] = sim[i][j] ----
    if (bi != bj) {
        #pragma unroll
        for (int sj = 0; sj < 4; ++sj) {
            float s = 0.0f;
            #pragma unroll
            for (int si = 0; si < 4; ++si)
                #pragma unroll
                for (int r = 0; r < 4; ++r) s += acc[si][sj][r];
            s += __shfl_xor(s, 16);
            s += __shfl_xor(s, 32);
            if (quad == 0) {
                const int gcol = rowB0 + wc * 64 + sj * 16 + m;
                partials[(size_t)gcol * 128 + bi * 2 + wr] = s;
            }
        }
    }
}

// ------- Kernel 3: combine partials -> per-block loss sums (plain stores, no atomics)
__global__ __launch_bounds__(256) void combine_kernel(const float* __restrict__ partials,
                                                      const unsigned short* __restrict__ featsbf,
                                                      const int* __restrict__ y,
                                                      float* __restrict__ blockSums) {
    __shared__ float red[4];
    const int wave = threadIdx.x >> 6;
    const int lane = threadIdx.x & 63;
    const int row  = blockIdx.x * 4 + wave;

    float L = partials[(size_t)row * 128 + lane] + partials[(size_t)row * 128 + 64 + lane];
    #pragma unroll
    for (int msk = 1; msk < 64; msk <<= 1) L += __shfl_xor(L, msk);
    float lse = INV_T + __logf(L);   // LSE = 1/T + log sum exp(l - 1/T)

    // target column c = y + (y >= row); dot(f_row, f_c) in bf16->fp32
    const int yv = y[row];
    const int c  = yv + (yv >= row ? 1 : 0);
    uint4 av = ((const uint4*)(featsbf + (size_t)row * ND))[lane];
    uint4 bv = ((const uint4*)(featsbf + (size_t)c   * ND))[lane];
    float dot = 0.0f;
    const unsigned int* au = (const unsigned int*)&av;
    const unsigned int* bu = (const unsigned int*)&bv;
    #pragma unroll
    for (int k = 0; k < 4; ++k) {
        dot += bf2f((unsigned short)(au[k] & 0xffffu)) * bf2f((unsigned short)(bu[k] & 0xffffu));
        dot += bf2f((unsigned short)(au[k] >> 16))     * bf2f((unsigned short)(bu[k] >> 16));
    }
    #pragma unroll
    for (int msk = 1; msk < 64; msk <<= 1) dot += __shfl_xor(dot, msk);

    float loss = lse - dot * INV_T;
    if (lane == 0) red[wave] = loss;
    __syncthreads();
    if (threadIdx.x == 0)
        blockSums[blockIdx.x] = red[0] + red[1] + red[2] + red[3];
}

// ------- Kernel 4: single-block final reduce of 2048 block sums; pack output ------
__global__ __launch_bounds__(256) void finish_kernel(const float* __restrict__ blockSums,
                                                     unsigned int* __restrict__ out) {
    __shared__ float red[4];
    const int wave = threadIdx.x >> 6;
    const int lane = threadIdx.x & 63;
    float s = 0.0f;
    #pragma unroll
    for (int k = 0; k < NBLK / 256; ++k) s += blockSums[threadIdx.x + 256 * k];
    #pragma unroll
    for (int msk = 1; msk < 64; msk <<= 1) s += __shfl_xor(s, msk);
    if (lane == 0) red[wave] = s;
    __syncthreads();
    if (threadIdx.x == 0) {
        float v = (red[0] + red[1] + red[2] + red[3]) * (1.0f / (float)NB);
        unsigned int b = f2bf(v);
        out[0] = (b << 16) | b;   // valid read as fp32 OR bf16
    }
}

extern "C" void kernel_launch(void* const* d_in, const int* in_sizes, int n_in,
                              void* d_out, int out_size, void* d_ws, size_t ws_size,
                              hipStream_t stream) {
    const float* x = (const float*)d_in[0];
    const int*   y = (const int*)d_in[1];

    // ws: [0,4M) fp8 feats (permuted); [4M,12M) bf16 feats; [12M,16M) partials; [16M..) blockSums
    unsigned char*  feats8    = (unsigned char*)d_ws;
    unsigned short* featsbf   = (unsigned short*)((char*)d_ws + (size_t)4 * 1024 * 1024);
    float*          partials  = (float*)((char*)d_ws + (size_t)12 * 1024 * 1024);
    float*          blockSums = (float*)((char*)d_ws + (size_t)16 * 1024 * 1024);

    norm_kernel<<<NB / 4, 256, 0, stream>>>(x, feats8, featsbf);
    const int ntiles = (NB / 128) * (NB / 128 + 1) / 2;   // 2080 upper-tri tiles
    sim_lse_kernel<<<ntiles, 256, 0, stream>>>(feats8, partials);
    combine_kernel<<<NBLK, 256, 0, stream>>>(partials, featsbf, y, blockSums);
    finish_kernel<<<1, 256, 0, stream>>>(blockSums, (unsigned int*)d_out);
}

// Round 9
// 114.155 us; speedup vs baseline: 1.0297x; 1.0297x over previous
//
#include <hip/hip_runtime.h>
#include <hip/hip_bf16.h>

// InfoNCE (n_views=1): loss = mean_i [ LSE_{j!=i}(f_i . f_j / T) - f_i . f_{c_i} / T ].
// FP8 (OCP e4m3) upper-triangle MFMA F F^T + fixed-max softmax partials.
// R9: double-buffered staging WITHOUT the R8 occupancy loss. BK=64 windows
// (the permuted layout already groups (kt,ks2) -> contiguous 64 B), two 8-KB
// buffers per array = 32 KB total LDS (5 blocks/CU cap, same as R7), prefetch
// window w+1 issued before compute(w) so the barrier's vmcnt drain is covered.
// Bank swizzle h(row) = (row ^ row>>2) & 3 spreads each quarter-wave evenly:
// 2 slots/bank = the b128 floor. (R8: 64 KB LDS halved occupancy, sim 38->52.)

typedef float f32x4 __attribute__((ext_vector_type(4)));
typedef long l2 __attribute__((ext_vector_type(2)));

#define AS1 __attribute__((address_space(1)))
#define AS3 __attribute__((address_space(3)))

constexpr int NB = 8192;   // batch
constexpr int ND = 512;    // dim
constexpr int NBLK = NB / 4;   // combine blocks (4 rows each)
constexpr float INV_T = 1.0f / 0.07f;

__device__ inline unsigned short f2bf(float f) {
    union { float f; unsigned int u; } v; v.f = f;
    unsigned int u = v.u;
    u = u + 0x7fffu + ((u >> 16) & 1u);   // round-to-nearest-even
    return (unsigned short)(u >> 16);
}
__device__ inline float bf2f(unsigned short s) {
    union { unsigned int u; float f; } v; v.u = ((unsigned int)s) << 16;
    return v.f;
}

// ------- Kernel 1: normalize rows; write PERMUTED fp8 feats + row-major bf16 -------
__global__ __launch_bounds__(256) void norm_kernel(const float* __restrict__ x,
                                                   unsigned char* __restrict__ feats8,
                                                   unsigned short* __restrict__ featsbf) {
    const int wave = threadIdx.x >> 6;
    const int lane = threadIdx.x & 63;
    const int row  = blockIdx.x * 4 + wave;
    const float4* xr = (const float4*)(x + (size_t)row * ND);
    float4 a = xr[2 * lane];       // cols 8*lane   .. +3
    float4 b = xr[2 * lane + 1];   // cols 8*lane+4 .. +7
    float ss = a.x*a.x + a.y*a.y + a.z*a.z + a.w*a.w
             + b.x*b.x + b.y*b.y + b.z*b.z + b.w*b.w;
    #pragma unroll
    for (int m = 32; m >= 1; m >>= 1) ss += __shfl_xor(ss, m);
    float scale = 1.0f / fmaxf(sqrtf(ss), 1e-12f);
    a.x *= scale; a.y *= scale; a.z *= scale; a.w *= scale;
    b.x *= scale; b.y *= scale; b.z *= scale; b.w *= scale;

    // bf16 copy, row-major (contiguous 8 shorts per lane) — used by combine's dot
    uint4 ub;
    ub.x = (unsigned)f2bf(a.x) | ((unsigned)f2bf(a.y) << 16);
    ub.y = (unsigned)f2bf(a.z) | ((unsigned)f2bf(a.w) << 16);
    ub.z = (unsigned)f2bf(b.x) | ((unsigned)f2bf(b.y) << 16);
    ub.w = (unsigned)f2bf(b.z) | ((unsigned)f2bf(b.w) << 16);
    ((uint4*)(featsbf + (size_t)row * ND))[lane] = ub;

    // fp8 e4m3, PERMUTED: lane holds original 8-B piece L (k = 8L..8L+7), i.e.
    // kt = L>>4, ks = (L>>2)&3, q = L&3.  New 8-B slot within the row:
    //   slot = kt*16 + (ks2*4 + q)*2 + (ks&1),  ks2 = ks>>1
    // => 16-B unit U = kt*8 + ks2*4 + q; 64-B window w = 2kt+ks2 holds the
    //    quad fragments for k-step pair (2w, 2w+1).
    int w0 = __builtin_amdgcn_cvt_pk_fp8_f32(a.x, a.y, 0, false);
    w0     = __builtin_amdgcn_cvt_pk_fp8_f32(a.z, a.w, w0, true);
    int w1 = __builtin_amdgcn_cvt_pk_fp8_f32(b.x, b.y, 0, false);
    w1     = __builtin_amdgcn_cvt_pk_fp8_f32(b.z, b.w, w1, true);
    uint2 u8; u8.x = (unsigned)w0; u8.y = (unsigned)w1;
    const int L    = lane;
    const int slot = ((L >> 4) << 4) + ((((L >> 3) & 1) * 4 + (L & 3)) << 1) + ((L >> 2) & 1);
    ((uint2*)(feats8 + (size_t)row * ND))[slot] = u8;
}

// ------- Kernel 2: upper-tri 128x128 tiles, fp8 MFMA, BK=64 double-buffered -------
// 2080 blocks -> (bi <= bj). 4 waves = 2x2 quadrants of 64x64.
// LDS(row, lq) = G(row, w, lq ^ h(row)), h(row) = (row ^ row>>2) & 3.
// Reader: unit (quad ^ h(m)) as one ds_read_b128 = k-steps 2w (lo 8B), 2w+1 (hi).
__global__ __launch_bounds__(256) void sim_lse_kernel(const unsigned char* __restrict__ feats8,
                                                      float* __restrict__ partials) {
    __shared__ unsigned char sA[2][128 * 64];
    __shared__ unsigned char sB[2][128 * 64];

    const int tid  = threadIdx.x;
    const int lane = tid & 63;
    const int wave = tid >> 6;
    const int wr   = wave >> 1;     // wave row quadrant (0..1)
    const int wc   = wave & 1;      // wave col quadrant (0..1)

    // decode upper-triangle pair: t -> (bi <= bj)
    int t = blockIdx.x;
    int bj = (int)((sqrtf(8.0f * (float)t + 1.0f) - 1.0f) * 0.5f);
    while ((bj + 1) * (bj + 2) / 2 <= t) ++bj;
    while (bj * (bj + 1) / 2 > t) --bj;
    const int bi = t - bj * (bj + 1) / 2;

    const int rowA0 = bi * 128;
    const int rowB0 = bj * 128;

    f32x4 acc[4][4] = {};

    const int m    = lane & 15;
    const int quad = lane >> 4;
    const int hm   = (m & 3) ^ ((m >> 2) & 3);   // h(tile row) — row ≡ m (mod 16)
    const int uoff = (quad ^ hm) << 4;           // swizzled 16-B unit offset

    auto stage = [&](int buf, int w) {
        const int k0 = w * 64;        // byte offset of window w in the 512-B row
        #pragma unroll
        for (int r = 0; r < 2; ++r) {
            int c   = r * 256 + tid;  // 16-B chunk id (512 per array per window)
            int row = c >> 2;
            int gq  = (c & 3) ^ ((row ^ (row >> 2)) & 3);
            const unsigned char* ga = feats8 + (size_t)(rowA0 + row) * ND + k0 + gq * 16;
            const unsigned char* gb = feats8 + (size_t)(rowB0 + row) * ND + k0 + gq * 16;
            __builtin_amdgcn_global_load_lds((const AS1 void*)ga, (AS3 void*)(&sA[buf][c * 16]), 16, 0, 0);
            __builtin_amdgcn_global_load_lds((const AS1 void*)gb, (AS3 void*)(&sB[buf][c * 16]), 16, 0, 0);
        }
    };
    auto compute = [&](int buf) {
        l2 afr[4], bfr[4];
        #pragma unroll
        for (int s = 0; s < 4; ++s) {
            afr[s] = *(const l2*)(&sA[buf][(wr * 64 + s * 16 + m) * 64 + uoff]);
            bfr[s] = *(const l2*)(&sB[buf][(wc * 64 + s * 16 + m) * 64 + uoff]);
        }
        #pragma unroll
        for (int e = 0; e < 2; ++e)
            #pragma unroll
            for (int si = 0; si < 4; ++si)
                #pragma unroll
                for (int sj = 0; sj < 4; ++sj)
                    acc[si][sj] = __builtin_amdgcn_mfma_f32_16x16x32_fp8_fp8(
                        afr[si][e], bfr[sj][e], acc[si][sj], 0, 0, 0);
    };

    // Pipeline: prefetch window w+1 into the idle 8-KB buffer, compute w, then
    // one barrier (drains the prefetch, overlapped with compute; also fences
    // buf[cur] reads before it is re-staged at w+2).
    stage(0, 0);
    __syncthreads();
    #pragma unroll
    for (int w = 0; w < 8; ++w) {
        const int cur = w & 1;
        if (w < 7) stage(1 - cur, w + 1);
        compute(cur);
        if (w < 7) __syncthreads();
    }

    // ---- Transform in place: acc <- exp((sim-1)/T), diagonal -> 0 ----
    // C/D layout (16x16x32, dtype-independent): col = lane&15, row = quad*4 + reg.
    const float C1 = INV_T * 1.4426950408889634f;   // log2(e)/T
    #pragma unroll
    for (int si = 0; si < 4; ++si) {
        #pragma unroll
        for (int sj = 0; sj < 4; ++sj) {
            const int gcol = rowB0 + wc * 64 + sj * 16 + m;
            #pragma unroll
            for (int r = 0; r < 4; ++r) {
                const int grow = rowA0 + wr * 64 + si * 16 + quad * 4 + r;
                float e = exp2f(fmaf(acc[si][sj][r], C1, -C1));
                acc[si][sj][r] = (grow == gcol) ? 0.0f : e;
            }
        }
    }

    // ---- Row pass: per-row sumexp over this wave's 64 cols ----
    #pragma unroll
    for (int si = 0; si < 4; ++si) {
        #pragma unroll
        for (int r = 0; r < 4; ++r) {
            float s = acc[si][0][r] + acc[si][1][r] + acc[si][2][r] + acc[si][3][r];
            #pragma unroll
            for (int msk = 1; msk < 16; msk <<= 1) s += __shfl_xor(s, msk);
            if (m == 0) {
                const int grow = rowA0 + wr * 64 + si * 16 + quad * 4 + r;
                partials[(size_t)grow * 128 + bj * 2 + wc] = s;
            }
        }
    }

    // ---- Col pass (off-diagonal tiles only): sim[j][i] = sim[i][j] ----
    if (bi != bj) {
        #pragma unroll
        for (int sj = 0; sj < 4; ++sj) {
            float s = 0.0f;
            #pragma unroll
            for (int si = 0; si < 4; ++si)
                #pragma unroll
                for (int r = 0; r < 4; ++r) s += acc[si][sj][r];
            s += __shfl_xor(s, 16);
            s += __shfl_xor(s, 32);
            if (quad == 0) {
                const int gcol = rowB0 + wc * 64 + sj * 16 + m;
                partials[(size_t)gcol * 128 + bi * 2 + wr] = s;
            }
        }
    }
}

// ------- Kernel 3: combine partials -> per-block loss sums (plain stores, no atomics)
__global__ __launch_bounds__(256) void combine_kernel(const float* __restrict__ partials,
                                                      const unsigned short* __restrict__ featsbf,
                                                      const int* __restrict__ y,
                                                      float* __restrict__ blockSums) {
    __shared__ float red[4];
    const int wave = threadIdx.x >> 6;
    const int lane = threadIdx.x & 63;
    const int row  = blockIdx.x * 4 + wave;

    float L = partials[(size_t)row * 128 + lane] + partials[(size_t)row * 128 + 64 + lane];
    #pragma unroll
    for (int msk = 1; msk < 64; msk <<= 1) L += __shfl_xor(L, msk);
    float lse = INV_T + __logf(L);   // LSE = 1/T + log sum exp(l - 1/T)

    // target column c = y + (y >= row); dot(f_row, f_c) in bf16->fp32
    const int yv = y[row];
    const int c  = yv + (yv >= row ? 1 : 0);
    uint4 av = ((const uint4*)(featsbf + (size_t)row * ND))[lane];
    uint4 bv = ((const uint4*)(featsbf + (size_t)c   * ND))[lane];
    float dot = 0.0f;
    const unsigned int* au = (const unsigned int*)&av;
    const unsigned int* bu = (const unsigned int*)&bv;
    #pragma unroll
    for (int k = 0; k < 4; ++k) {
        dot += bf2f((unsigned short)(au[k] & 0xffffu)) * bf2f((unsigned short)(bu[k] & 0xffffu));
        dot += bf2f((unsigned short)(au[k] >> 16))     * bf2f((unsigned short)(bu[k] >> 16));
    }
    #pragma unroll
    for (int msk = 1; msk < 64; msk <<= 1) dot += __shfl_xor(dot, msk);

    float loss = lse - dot * INV_T;
    if (lane == 0) red[wave] = loss;
    __syncthreads();
    if (threadIdx.x == 0)
        blockSums[blockIdx.x] = red[0] + red[1] + red[2] + red[3];
}

// ------- Kernel 4: single-block final reduce of 2048 block sums; pack output ------
__global__ __launch_bounds__(256) void finish_kernel(const float* __restrict__ blockSums,
                                                     unsigned int* __restrict__ out) {
    __shared__ float red[4];
    const int wave = threadIdx.x >> 6;
    const int lane = threadIdx.x & 63;
    float s = 0.0f;
    #pragma unroll
    for (int k = 0; k < NBLK / 256; ++k) s += blockSums[threadIdx.x + 256 * k];
    #pragma unroll
    for (int msk = 1; msk < 64; msk <<= 1) s += __shfl_xor(s, msk);
    if (lane == 0) red[wave] = s;
    __syncthreads();
    if (threadIdx.x == 0) {
        float v = (red[0] + red[1] + red[2] + red[3]) * (1.0f / (float)NB);
        unsigned int b = f2bf(v);
        out[0] = (b << 16) | b;   // valid read as fp32 OR bf16
    }
}

extern "C" void kernel_launch(void* const* d_in, const int* in_sizes, int n_in,
                              void* d_out, int out_size, void* d_ws, size_t ws_size,
                              hipStream_t stream) {
    const float* x = (const float*)d_in[0];
    const int*   y = (const int*)d_in[1];

    // ws: [0,4M) fp8 feats (permuted); [4M,12M) bf16 feats; [12M,16M) partials; [16M..) blockSums
    unsigned char*  feats8    = (unsigned char*)d_ws;
    unsigned short* featsbf   = (unsigned short*)((char*)d_ws + (size_t)4 * 1024 * 1024);
    float*          partials  = (float*)((char*)d_ws + (size_t)12 * 1024 * 1024);
    float*          blockSums = (float*)((char*)d_ws + (size_t)16 * 1024 * 1024);

    norm_kernel<<<NB / 4, 256, 0, stream>>>(x, feats8, featsbf);
    const int ntiles = (NB / 128) * (NB / 128 + 1) / 2;   // 2080 upper-tri tiles
    sim_lse_kernel<<<ntiles, 256, 0, stream>>>(feats8, partials);
    combine_kernel<<<NBLK, 256, 0, stream>>>(partials, featsbf, y, blockSums);
    finish_kernel<<<1, 256, 0, stream>>>(blockSums, (unsigned int*)d_out);
}